// Round 13
// baseline (62.299 us; speedup 1.0000x reference)
//
#include <hip/hip_runtime.h>
#include <math.h>

// LIFNeuronFDE: fractional-order LIF with Grunwald-Letnikov memory.
//   v^{k+1} = 2*(I_k - v^k) - sum_{j=0}^{k} c_{k+1-j} v^{(j)},  v^{(0)} = v0
//   spike_k = sigmoid(5*(v^{k+1} - 1))
// T=32, B=32, N=32768.  Linear-map form: v_{k+1} = b[k]*v0 + sum_j a[k][j] I_j.
//
// R12 falsified VALU-bound (43% fewer fp64 FMAs -> slower). R10 (48.6us,
// float2 + lazy cvt + nt stores) is the champion. FETCH pinned at 67.7MB
// regardless of nt => Infinity Cache is memory-side; I+out (268MB) > 256MB
// structurally thrashes ~67MB/replay to HBM. Effective request BW already
// 5.5 TB/s (~88% of copy ceiling). Last untested lever on the request path:
// ACCESS WIDTH. R13 = R10 at 4 elems/thread: dwordx4 loads + nt dwordx4
// stores (1KiB/wave-store), half the memory instructions, 2x per-thread MLP.
// Per-element fp64 fma order unchanged -> bitwise-identical output
// (absmax margin thin: 0.0176/0.02). If this doesn't move: roofline.

#define T_STEPS 32
#define BN (32 * 32768)              // B*N = 1,048,576 elements
#define QUADS (BN / 4)               // 262,144 float4 work items

typedef float f32x4 __attribute__((ext_vector_type(4)));

struct LinMap {
    double a[T_STEPS][T_STEPS];      // a[k][j]: coeff of I_j in v_{k+1} (j<=k)
    double b[T_STEPS];               // b[k]:    coeff of v0  in v_{k+1}
};

constexpr LinMap make_linmap() {
    // GL coefficients: c_0=1, c_j = (1 - 1.5/j) c_{j-1}
    double c[T_STEPS + 1] = {};
    c[0] = 1.0;
    for (int j = 1; j <= T_STEPS; ++j) c[j] = c[j - 1] * (1.0 - 1.5 / (double)j);

    // vc[k][m]: coefficient of basis element m in v_k (m=0 -> v0, m=1+j -> I_j)
    double vc[T_STEPS + 1][T_STEPS + 1] = {};
    vc[0][0] = 1.0;

    LinMap r{};
    for (int k = 0; k < T_STEPS; ++k) {
        // v_{k+1} = 2*I_k - 2*v_k - sum_{j=0}^{k} c[k+1-j] * v_j
        for (int m = 0; m <= T_STEPS; ++m) {
            double acc = -2.0 * vc[k][m];
            for (int j = 0; j <= k; ++j) acc -= c[k + 1 - j] * vc[j][m];
            vc[k + 1][m] = acc;
        }
        vc[k + 1][1 + k] += 2.0;

        r.b[k] = vc[k + 1][0];
        for (int j = 0; j < T_STEPS; ++j) r.a[k][j] = vc[k + 1][1 + j];
    }
    return r;
}

constexpr LinMap CM = make_linmap();

__device__ __forceinline__ float sigmoid5(const double s) {
    const float a = (float)(-5.0 * (s - 1.0));
    return 1.0f / (1.0f + __expf(a));
}

// Row K: s = b[K]*v0 + sum_{j=0}^{K} a[K][j]*I_j (fp64, lazy cvt, ascending
// j — identical per-element sequence to R10). All If[] indices literal.
template<int K>
__device__ __forceinline__ void fde_rows(const f32x4 (&If)[T_STEPS],
                                         const double v0a, const double v0b,
                                         const double v0c, const double v0d,
                                         f32x4* __restrict__ out4,
                                         const int idx)
{
    if constexpr (K < T_STEPS) {
        double sa = CM.b[K] * v0a;
        double sb = CM.b[K] * v0b;
        double sc = CM.b[K] * v0c;
        double sd = CM.b[K] * v0d;
        #pragma unroll
        for (int j = 0; j <= K; ++j) {
            sa = fma(CM.a[K][j], (double)If[j].x, sa);
            sb = fma(CM.a[K][j], (double)If[j].y, sb);
            sc = fma(CM.a[K][j], (double)If[j].z, sc);
            sd = fma(CM.a[K][j], (double)If[j].w, sd);
        }
        f32x4 sp;
        sp.x = sigmoid5(sa);
        sp.y = sigmoid5(sb);
        sp.z = sigmoid5(sc);
        sp.w = sigmoid5(sd);
        // Non-temporal store (R10's win): zero-reuse stream, 16B/lane.
        __builtin_nontemporal_store(sp, &out4[(size_t)K * QUADS + idx]);

        fde_rows<K + 1>(If, v0a, v0b, v0c, v0d, out4, idx);
    }
}

__global__ __launch_bounds__(256) void lif_fde_kernel(
    const float* __restrict__ I,
    const float* __restrict__ v0,
    float* __restrict__ out)
{
    const int idx = blockIdx.x * blockDim.x + threadIdx.x;   // [0, QUADS)

    const f32x4* __restrict__ I4   = (const f32x4*)I;
    const f32x4* __restrict__ v04  = (const f32x4*)v0;
    f32x4* __restrict__       out4 = (f32x4*)out;

    // Stage all of I for this quad (fp32, exact): 32 independent dwordx4
    // loads -> one pipelined latency hit, 1KiB/wave-instruction.
    f32x4 If[T_STEPS];
    #pragma unroll
    for (int k = 0; k < T_STEPS; ++k) {
        If[k] = I4[(size_t)k * QUADS + idx];
    }

    const f32x4 v0f = v04[idx];
    const double v0a = (double)v0f.x;
    const double v0b = (double)v0f.y;
    const double v0c = (double)v0f.z;
    const double v0d = (double)v0f.w;

    fde_rows<0>(If, v0a, v0b, v0c, v0d, out4, idx);
}

extern "C" void kernel_launch(void* const* d_in, const int* in_sizes, int n_in,
                              void* d_out, int out_size, void* d_ws, size_t ws_size,
                              hipStream_t stream) {
    const float* I  = (const float*)d_in[0];   // (T, B, N) fp32
    const float* v0 = (const float*)d_in[1];   // (B, N) fp32
    float* out = (float*)d_out;                // (T, B, N) fp32

    dim3 block(256);
    dim3 grid(QUADS / 256);                    // 1024 blocks, exact fit
    lif_fde_kernel<<<grid, block, 0, stream>>>(I, v0, out);
}

// Round 14
// 62.101 us; speedup vs baseline: 1.0032x; 1.0032x over previous
//
#include <hip/hip_runtime.h>
#include <math.h>

// LIFNeuronFDE: fractional-order LIF with Grunwald-Letnikov memory.
//   v^{k+1} = 2*(I_k - v^k) - sum_{j=0}^{k} c_{k+1-j} v^{(j)},  v^{(0)} = v0
//   spike_k = sigmoid(5*(v^{k+1} - 1))
// T=32, B=32, N=32768.  Linear-map form: v_{k+1} = b[k]*v0 + sum_j a[k][j] I_j.
//
// Standing results: R10 (float2 gather + lazy cvt + nt store) = 48.6us champ.
// R11 (cvt placement), R12 (-43% fp64), R13 (16B width) all regressed ->
// neither VALU nor occupancy nor width is the lever. Steady state:
// FETCH 67.7MB + WRITE 131MB = 199MB HBM @ 4.1 TB/s; request stream 5.5 TB/s
// (88% of copy ceiling). Anomaly: I (134MB) fits L3, yet FETCH == half of I
// -> the nt store still ALLOCATES in the memory-side Infinity Cache and
// evicts I every replay (nt only fixed L2 policy = R10's win).
//
// R14 (this): store via inline asm "global_store_dwordx2 ... sc0 sc1 nt"
// (system-scope + non-temporal = strongest write-around gfx950 encodes).
// If the LLC stops allocating writes, I stays L3-resident across replays:
// FETCH should collapse ~67MB (~10us). Same stored values -> bit-identical
// output (absmax margin thin: 0.0176/0.02). If FETCH/dur unchanged ->
// mixed-stream memory roofline reached; declare ROOFLINE next round.

#define T_STEPS 32
#define BN (32 * 32768)              // B*N = 1,048,576 elements
#define PAIRS (BN / 2)               // 524,288 float2 work items

typedef float f32x2 __attribute__((ext_vector_type(2)));

struct LinMap {
    double a[T_STEPS][T_STEPS];      // a[k][j]: coeff of I_j in v_{k+1} (j<=k)
    double b[T_STEPS];               // b[k]:    coeff of v0  in v_{k+1}
};

constexpr LinMap make_linmap() {
    // GL coefficients: c_0=1, c_j = (1 - 1.5/j) c_{j-1}
    double c[T_STEPS + 1] = {};
    c[0] = 1.0;
    for (int j = 1; j <= T_STEPS; ++j) c[j] = c[j - 1] * (1.0 - 1.5 / (double)j);

    // vc[k][m]: coefficient of basis element m in v_k (m=0 -> v0, m=1+j -> I_j)
    double vc[T_STEPS + 1][T_STEPS + 1] = {};
    vc[0][0] = 1.0;

    LinMap r{};
    for (int k = 0; k < T_STEPS; ++k) {
        // v_{k+1} = 2*I_k - 2*v_k - sum_{j=0}^{k} c[k+1-j] * v_j
        for (int m = 0; m <= T_STEPS; ++m) {
            double acc = -2.0 * vc[k][m];
            for (int j = 0; j <= k; ++j) acc -= c[k + 1 - j] * vc[j][m];
            vc[k + 1][m] = acc;
        }
        vc[k + 1][1 + k] += 2.0;

        r.b[k] = vc[k + 1][0];
        for (int j = 0; j < T_STEPS; ++j) r.a[k][j] = vc[k + 1][1 + j];
    }
    return r;
}

constexpr LinMap CM = make_linmap();

// System-scope non-temporal streaming store: write-around all caches so the
// zero-reuse output stream stops evicting I from the Infinity Cache.
__device__ __forceinline__ void store_stream(f32x2* p, f32x2 v) {
    asm volatile("global_store_dwordx2 %0, %1, off sc0 sc1 nt"
                 :: "v"(p), "v"(v) : "memory");
}

// Row K: s = b[K]*v0 + sum_{j=0}^{K} a[K][j]*I_j (fp64, lazy cvt, ascending
// j — identical per-element sequence to R10). All If[] indices literal.
template<int K>
__device__ __forceinline__ void fde_rows(const float2 (&If)[T_STEPS],
                                         const double v0x, const double v0y,
                                         f32x2* __restrict__ out2,
                                         const int idx)
{
    if constexpr (K < T_STEPS) {
        double sx = CM.b[K] * v0x;
        double sy = CM.b[K] * v0y;
        #pragma unroll
        for (int j = 0; j <= K; ++j) {
            sx = fma(CM.a[K][j], (double)If[j].x, sx);
            sy = fma(CM.a[K][j], (double)If[j].y, sy);
        }
        const float ax = (float)(-5.0 * (sx - 1.0));
        const float ay = (float)(-5.0 * (sy - 1.0));
        f32x2 sp;
        sp.x = 1.0f / (1.0f + __expf(ax));
        sp.y = 1.0f / (1.0f + __expf(ay));
        store_stream(&out2[(size_t)K * PAIRS + idx], sp);

        fde_rows<K + 1>(If, v0x, v0y, out2, idx);
    }
}

__global__ __launch_bounds__(256) void lif_fde_kernel(
    const float* __restrict__ I,
    const float* __restrict__ v0,
    float* __restrict__ out)
{
    const int idx = blockIdx.x * blockDim.x + threadIdx.x;   // [0, PAIRS)

    const float2* __restrict__ I2   = (const float2*)I;
    const float2* __restrict__ v02  = (const float2*)v0;
    f32x2* __restrict__        out2 = (f32x2*)out;

    // Stage all of I for this pair in fp32 registers (exact), issued as 32
    // independent dwordx2 loads -> one pipelined latency hit.
    float2 If[T_STEPS];
    #pragma unroll
    for (int k = 0; k < T_STEPS; ++k) {
        If[k] = I2[(size_t)k * PAIRS + idx];
    }

    const float2 v0f = v02[idx];
    const double v0x = (double)v0f.x;
    const double v0y = (double)v0f.y;

    fde_rows<0>(If, v0x, v0y, out2, idx);
}

extern "C" void kernel_launch(void* const* d_in, const int* in_sizes, int n_in,
                              void* d_out, int out_size, void* d_ws, size_t ws_size,
                              hipStream_t stream) {
    const float* I  = (const float*)d_in[0];   // (T, B, N) fp32
    const float* v0 = (const float*)d_in[1];   // (B, N) fp32
    float* out = (float*)d_out;                // (T, B, N) fp32

    dim3 block(256);
    dim3 grid(PAIRS / 256);                    // 2048 blocks, exact fit
    lif_fde_kernel<<<grid, block, 0, stream>>>(I, v0, out);
}

// Round 15
// 59.921 us; speedup vs baseline: 1.0397x; 1.0364x over previous
//
#include <hip/hip_runtime.h>
#include <math.h>

// LIFNeuronFDE: fractional-order LIF with Grunwald-Letnikov memory.
//   v^{k+1} = 2*(I_k - v^k) - sum_{j=0}^{k} c_{k+1-j} v^{(j)},  v^{(0)} = v0
//   spike_k = sigmoid(5*(v^{k+1} - 1))
// T=32, B=32, N=32768.  Linear-map form: v_{k+1} = b[k]*v0 + sum_j a[k][j] I_j.
//
// CHAMPION (R10, 48.6us) resubmitted verbatim. Lever matrix closed:
//  - width: 8B/lane optimal (4B: +13%, 16B: +28%)
//  - occupancy 11-64%: uncorrelated with time
//  - fp64 count -43% (R12): slower -> not VALU-bound
//  - cvt placement/phasing/laundering: neutral or worse
//  - nt store (L2 policy): -7.1us  <- the one win
//  - LLC write-around sc0 sc1 nt (R14): slower; FETCH pinned at 67.7MB
// Budget: 268MB request stream -> 42.6us at 6.29TB/s copy ceiling; this
// kernel = 88% of that; residual = structural LLC thrash (I+out = 268MB >
// 256MB L3; memory-side LLC allocates writes regardless of store policy)
// + mixed R/W turnaround. This is the access-pattern roofline.

#define T_STEPS 32
#define BN (32 * 32768)              // B*N = 1,048,576 elements
#define PAIRS (BN / 2)               // 524,288 float2 work items

typedef float f32x2 __attribute__((ext_vector_type(2)));

struct LinMap {
    double a[T_STEPS][T_STEPS];      // a[k][j]: coeff of I_j in v_{k+1} (j<=k)
    double b[T_STEPS];               // b[k]:    coeff of v0  in v_{k+1}
};

constexpr LinMap make_linmap() {
    // GL coefficients: c_0=1, c_j = (1 - 1.5/j) c_{j-1}
    double c[T_STEPS + 1] = {};
    c[0] = 1.0;
    for (int j = 1; j <= T_STEPS; ++j) c[j] = c[j - 1] * (1.0 - 1.5 / (double)j);

    // vc[k][m]: coefficient of basis element m in v_k (m=0 -> v0, m=1+j -> I_j)
    double vc[T_STEPS + 1][T_STEPS + 1] = {};
    vc[0][0] = 1.0;

    LinMap r{};
    for (int k = 0; k < T_STEPS; ++k) {
        // v_{k+1} = 2*I_k - 2*v_k - sum_{j=0}^{k} c[k+1-j] * v_j
        for (int m = 0; m <= T_STEPS; ++m) {
            double acc = -2.0 * vc[k][m];
            for (int j = 0; j <= k; ++j) acc -= c[k + 1 - j] * vc[j][m];
            vc[k + 1][m] = acc;
        }
        vc[k + 1][1 + k] += 2.0;

        r.b[k] = vc[k + 1][0];
        for (int j = 0; j < T_STEPS; ++j) r.a[k][j] = vc[k + 1][1 + j];
    }
    return r;
}

constexpr LinMap CM = make_linmap();

// Row K: s = b[K]*v0 + sum_{j=0}^{K} a[K][j]*I_j (fp64, ascending j),
// then spike = sigmoid(5*(s-1)). All If[] indices are compile-time literals.
template<int K>
__device__ __forceinline__ void fde_rows(const float2 (&If)[T_STEPS],
                                         const double v0x, const double v0y,
                                         f32x2* __restrict__ out2,
                                         const int idx)
{
    if constexpr (K < T_STEPS) {
        double sx = CM.b[K] * v0x;
        double sy = CM.b[K] * v0y;
        #pragma unroll
        for (int j = 0; j <= K; ++j) {
            sx = fma(CM.a[K][j], (double)If[j].x, sx);
            sy = fma(CM.a[K][j], (double)If[j].y, sy);
        }
        const float ax = (float)(-5.0 * (sx - 1.0));
        const float ay = (float)(-5.0 * (sy - 1.0));
        f32x2 sp;
        sp.x = 1.0f / (1.0f + __expf(ax));
        sp.y = 1.0f / (1.0f + __expf(ay));
        // Non-temporal store: output has zero reuse; keep it out of L3 so
        // I stays resident across replays.
        __builtin_nontemporal_store(sp, &out2[(size_t)K * PAIRS + idx]);

        fde_rows<K + 1>(If, v0x, v0y, out2, idx);
    }
}

__global__ __launch_bounds__(256) void lif_fde_kernel(
    const float* __restrict__ I,
    const float* __restrict__ v0,
    float* __restrict__ out)
{
    const int idx = blockIdx.x * blockDim.x + threadIdx.x;   // [0, PAIRS)

    const float2* __restrict__ I2   = (const float2*)I;
    const float2* __restrict__ v02  = (const float2*)v0;
    f32x2* __restrict__        out2 = (f32x2*)out;

    // Stage all of I for this pair in fp32 registers (exact), issued as 32
    // independent dwordx2 loads -> one pipelined latency hit.
    float2 If[T_STEPS];
    #pragma unroll
    for (int k = 0; k < T_STEPS; ++k) {
        If[k] = I2[(size_t)k * PAIRS + idx];
    }

    const float2 v0f = v02[idx];
    const double v0x = (double)v0f.x;
    const double v0y = (double)v0f.y;

    fde_rows<0>(If, v0x, v0y, out2, idx);
}

extern "C" void kernel_launch(void* const* d_in, const int* in_sizes, int n_in,
                              void* d_out, int out_size, void* d_ws, size_t ws_size,
                              hipStream_t stream) {
    const float* I  = (const float*)d_in[0];   // (T, B, N) fp32
    const float* v0 = (const float*)d_in[1];   // (B, N) fp32
    float* out = (float*)d_out;                // (T, B, N) fp32

    dim3 block(256);
    dim3 grid(PAIRS / 256);                    // 2048 blocks, exact fit
    lif_fde_kernel<<<grid, block, 0, stream>>>(I, v0, out);
}